// Round 16
// baseline (38.072 us; speedup 1.0000x reference)
//
#include <hip/hip_runtime.h>

#define HWX 9216
#define CIN 64
#define COUT 64
#define SR 14
#define SC 24
#define SLOT 144          // bytes per staged pixel (128 data + 16 pad -> bank spread)

typedef __attribute__((ext_vector_type(8))) short short8;
typedef __attribute__((ext_vector_type(8))) _Float16 half8;
typedef __attribute__((ext_vector_type(2))) _Float16 half2v;
typedef __attribute__((ext_vector_type(4))) float f32x4;
typedef __attribute__((ext_vector_type(4))) unsigned int u32x4;

__device__ inline unsigned short f2h(float f) {
    union { _Float16 h; unsigned short u; } v;
    v.h = (_Float16)f;
    return v.u;
}
__device__ inline unsigned pack2h(float lo, float hi) {
    return (unsigned)f2h(lo) | ((unsigned)f2h(hi) << 16);
}

// NCHW f32 -> NHWC f16 (packed 2 channels per u32)
__global__ __launch_bounds__(256) void nchw_to_nhwc_f16(const float* __restrict__ x,
                                                        unsigned* __restrict__ xt) {
    __shared__ float tile[64][65];
    int n  = blockIdx.x / 144;
    int p0 = (blockIdx.x % 144) * 64;
    const float* xp = x + (size_t)n * CIN * HWX + p0;
    #pragma unroll
    for (int it = 0; it < 16; ++it) {
        int px = threadIdx.x & 63;
        int c  = (threadIdx.x >> 6) + it * 4;
        tile[c][px] = xp[c * HWX + px];
    }
    __syncthreads();
    unsigned* xo = xt + ((size_t)n * HWX + p0) * 32;
    #pragma unroll
    for (int it = 0; it < 8; ++it) {
        int c2 = threadIdx.x & 31;
        int px = (threadIdx.x >> 5) + it * 8;
        xo[px * 32 + c2] = pack2h(tile[2 * c2][px], tile[2 * c2 + 1][px]);
    }
}

// wA fragment layout: idx = ((step*4 + m0)*64 + lane)*8 + j  (f16 elements)
// W[co = m0*16 + (lane&15)][kg = step*32 + (lane>>4)*8 + j], kg = kk*64 + c
__global__ void dcn_prep_weight(const float* __restrict__ w, unsigned short* __restrict__ wA) {
    int idx = blockIdx.x * blockDim.x + threadIdx.x;  // 36864 threads
    int j    = idx & 7;
    int lane = (idx >> 3) & 63;
    int m0   = (idx >> 9) & 3;
    int step = idx >> 11;
    int co = m0 * 16 + (lane & 15);
    int kg = step * 32 + ((lane >> 4) << 3) + j;
    int kk = kg >> 6;
    int c  = kg & 63;
    wA[idx] = f2h(w[(co * 64 + c) * 9 + kk]);
}

// 16x6 output tile, 6 waves/block, 768 blocks = exactly 3 blocks/CU (zero
// tail), f16 sampling pipeline. R16 = R15 retry without macros: 1-unit
// software pipeline at half-tap granularity (18 units = 9 taps x 2 halves),
// expressed as a fully-unrolled C++ loop so every buffer index is a
// compile-time constant (rule #20). PREP(u) issues unit u's 4 ds_read_b128
// + rare global fallback; CONSUME(u-1) blends+MFMAs the PREVIOUS unit, so
// lgkm/vmcnt waits land after ~1 unit of independent compute.
__global__ __launch_bounds__(384, 4) void dcn_fwd(const unsigned short* __restrict__ xt,
                                                  const float* __restrict__ offset,
                                                  const float* __restrict__ mask,
                                                  const unsigned short* __restrict__ wA,
                                                  float* __restrict__ out) {
    __shared__ __align__(16) char ldsx[SR * SC * SLOT];   // 48,384 B

    int bid = blockIdx.x;
    int swz = (bid & 7) * 96 + (bid >> 3);   // bijective XCD swizzle (768 = 8*96)
    int n   = swz / 96;                      // image <-> XCD
    int t0  = swz % 96;
    int r0  = (t0 / 6) * 6;                  // tile origin: 16 wide x 6 tall
    int c0  = (t0 % 6) * 16;

    int sy0 = r0 - 4;          // fixed window, clamped staging
    int sx0 = c0 - 4;

    const unsigned short* xn = xt + (size_t)n * HWX * 64;

    int wave = threadIdx.x >> 6;
    int lane = threadIdx.x & 63;
    int l15  = lane & 15;
    int lg   = lane >> 4;

    int ho = r0 + wave;
    int wo = c0 + l15;

    // stage 14x24 window: 2688 16B chunks = 7 iters * 384 threads
    #pragma unroll
    for (int it = 0; it < 7; ++it) {
        int i  = threadIdx.x + it * 384;
        int s  = i >> 3, ch = i & 7;
        int ly = s / SC, lx = s - ly * SC;
        int gy = min(max(sy0 + ly, 0), 95);
        int gx = min(max(sx0 + lx, 0), 95);
        *(u32x4*)(ldsx + s * SLOT + ch * 16) =
            *((const u32x4*)(xn + (gy * 96 + gx) * 64) + ch);
    }
    __syncthreads();

    typedef union { u32x4 u; half2v h[4]; } U;

    f32x4 acc[4] = {f32x4{0,0,0,0}, f32x4{0,0,0,0}, f32x4{0,0,0,0}, f32x4{0,0,0,0}};

    U buf[2][4];                 // double-buffered samples (corner 00,01,10,11)
    half2v Wt[2][4];             // per-tap blend weights, 2 tap-parities
    int sS0 = 0, sS1 = 0, sS2 = 0, sS3 = 0;   // LDS byte offsets, current tap
    int gS0 = 0, gS1 = 0, gS2 = 0, gS3 = 0;   // global element offsets (fallback)
    bool locS = true;            // current tap fully inside staged window?
    float dyn_, dxn_, mn_;       // rolling offsets (loaded one tap ahead)

    // load offsets for tap 0
    dyn_ = offset[((n * 18 + 0) * 96 + ho) * 96 + wo];
    dxn_ = offset[((n * 18 + 1) * 96 + ho) * 96 + wo];
    mn_  = mask[((n * 9 + 0) * 96 + ho) * 96 + wo];

    // software pipeline: stage u does PREP(u) then CONSUME(u-1)
    #pragma unroll
    for (int u = 0; u <= 18; ++u) {
        if (u < 18) {
            // ---------------- PREP(u) ----------------
            const int tp = u >> 1;
            const int hp = u & 1;
            if (hp == 0) {
                float dy = dyn_, dx = dxn_, mm = mn_;
                if (tp < 8) {
                    dyn_ = offset[((n * 18 + 2 * (tp + 1) + 0) * 96 + ho) * 96 + wo];
                    dxn_ = offset[((n * 18 + 2 * (tp + 1) + 1) * 96 + ho) * 96 + wo];
                    mn_  = mask[((n * 9 + (tp + 1)) * 96 + ho) * 96 + wo];
                }
                float py = dy + (float)(tp / 3 + ho - 1);
                float px = dx + (float)(tp % 3 + wo - 1);
                float y0f = floorf(py), x0f = floorf(px);
                float wy1 = py - y0f, wx1 = px - x0f;
                float wy0 = 1.f - wy1, wx0 = 1.f - wx1;
                int y0 = (int)y0f, x0 = (int)x0f;
                int y1 = y0 + 1, x1 = x0 + 1;
                bool vy0 = (y0 >= 0) && (y0 < 96);
                bool vy1 = (y1 >= 0) && (y1 < 96);
                bool vx0 = (x0 >= 0) && (x0 < 96);
                bool vx1 = (x1 >= 0) && (x1 < 96);
                int y0c = min(max(y0, 0), 95), y1c = min(max(y1, 0), 95);
                int x0c = min(max(x0, 0), 95), x1c = min(max(x1, 0), 95);
                float w00 = wy0 * wx0 * mm * ((vy0 && vx0) ? 1.f : 0.f);
                float w01 = wy0 * wx1 * mm * ((vy0 && vx1) ? 1.f : 0.f);
                float w10 = wy1 * wx0 * mm * ((vy1 && vx0) ? 1.f : 0.f);
                float w11 = wy1 * wx1 * mm * ((vy1 && vx1) ? 1.f : 0.f);
                _Float16 h00 = (_Float16)w00, h01 = (_Float16)w01;
                _Float16 h10 = (_Float16)w10, h11 = (_Float16)w11;
                Wt[tp & 1][0] = (half2v){h00, h00};
                Wt[tp & 1][1] = (half2v){h01, h01};
                Wt[tp & 1][2] = (half2v){h10, h10};
                Wt[tp & 1][3] = (half2v){h11, h11};
                locS = (y0c >= sy0) && (y1c <= sy0 + SR - 1) &&
                       (x0c >= sx0) && (x1c <= sx0 + SC - 1);
                int ly0 = min(max(y0c - sy0, 0), SR - 1);
                int ly1 = min(max(y1c - sy0, 0), SR - 1);
                int lx0 = min(max(x0c - sx0, 0), SC - 1);
                int lx1 = min(max(x1c - sx0, 0), SC - 1);
                sS0 = (ly0 * SC + lx0) * SLOT; sS1 = (ly0 * SC + lx1) * SLOT;
                sS2 = (ly1 * SC + lx0) * SLOT; sS3 = (ly1 * SC + lx1) * SLOT;
                gS0 = (y0c * 96 + x0c) * 64; gS1 = (y0c * 96 + x1c) * 64;
                gS2 = (y1c * 96 + x0c) * 64; gS3 = (y1c * 96 + x1c) * 64;
            }
            {
                const int oh = hp ? (64 + lg * 16) : (lg * 16);
                buf[hp][0].u = *(const u32x4*)(ldsx + sS0 + oh);
                buf[hp][1].u = *(const u32x4*)(ldsx + sS1 + oh);
                buf[hp][2].u = *(const u32x4*)(ldsx + sS2 + oh);
                buf[hp][3].u = *(const u32x4*)(ldsx + sS3 + oh);
                if (__builtin_expect(!locS, 0)) {
                    const int ch = hp ? (32 + lg * 8) : (lg * 8);
                    buf[hp][0].u = *(const u32x4*)(xn + gS0 + ch);
                    buf[hp][1].u = *(const u32x4*)(xn + gS1 + ch);
                    buf[hp][2].u = *(const u32x4*)(xn + gS2 + ch);
                    buf[hp][3].u = *(const u32x4*)(xn + gS3 + ch);
                }
            }
        }
        if (u > 0) {
            // ---------------- CONSUME(u-1) ----------------
            const int v  = u - 1;
            const int tc = v >> 1;
            const int hc = v & 1;
            U r_;
            r_.h[0] = buf[hc][0].h[0] * Wt[tc & 1][0] + buf[hc][1].h[0] * Wt[tc & 1][1]
                    + buf[hc][2].h[0] * Wt[tc & 1][2] + buf[hc][3].h[0] * Wt[tc & 1][3];
            r_.h[1] = buf[hc][0].h[1] * Wt[tc & 1][0] + buf[hc][1].h[1] * Wt[tc & 1][1]
                    + buf[hc][2].h[1] * Wt[tc & 1][2] + buf[hc][3].h[1] * Wt[tc & 1][3];
            r_.h[2] = buf[hc][0].h[2] * Wt[tc & 1][0] + buf[hc][1].h[2] * Wt[tc & 1][1]
                    + buf[hc][2].h[2] * Wt[tc & 1][2] + buf[hc][3].h[2] * Wt[tc & 1][3];
            r_.h[3] = buf[hc][0].h[3] * Wt[tc & 1][0] + buf[hc][1].h[3] * Wt[tc & 1][1]
                    + buf[hc][2].h[3] * Wt[tc & 1][2] + buf[hc][3].h[3] * Wt[tc & 1][3];
            half8 bf_ = *(half8*)&r_;
            const half8* wp_ = (const half8*)(wA + ((v) * 256 + lane) * 8);
            acc[0] = __builtin_amdgcn_mfma_f32_16x16x32_f16(wp_[0],   bf_, acc[0], 0, 0, 0);
            acc[1] = __builtin_amdgcn_mfma_f32_16x16x32_f16(wp_[64],  bf_, acc[1], 0, 0, 0);
            acc[2] = __builtin_amdgcn_mfma_f32_16x16x32_f16(wp_[128], bf_, acc[2], 0, 0, 0);
            acc[3] = __builtin_amdgcn_mfma_f32_16x16x32_f16(wp_[192], bf_, acc[3], 0, 0, 0);
        }
    }

    // D: lane l, reg r -> co = m0*16 + lg*4 + r, pixel col = l15
    size_t obase = (size_t)n * COUT * HWX + (size_t)ho * 96 + wo;
    #pragma unroll
    for (int m0 = 0; m0 < 4; ++m0) {
        #pragma unroll
        for (int r = 0; r < 4; ++r) {
            int co = m0 * 16 + lg * 4 + r;
            out[obase + (size_t)co * HWX] = acc[m0][r];
        }
    }
}

extern "C" void kernel_launch(void* const* d_in, const int* in_sizes, int n_in,
                              void* d_out, int out_size, void* d_ws, size_t ws_size,
                              hipStream_t stream) {
    const float* x      = (const float*)d_in[0];
    const float* offset = (const float*)d_in[1];
    const float* mask   = (const float*)d_in[2];
    const float* w      = (const float*)d_in[3];
    float* out = (float*)d_out;
    unsigned* xt       = (unsigned*)d_ws;                                    // 9,437,184 B
    unsigned short* wA = (unsigned short*)((char*)d_ws + (size_t)8 * HWX * 64 * 2); // +73,728 B

    hipLaunchKernelGGL(nchw_to_nhwc_f16, dim3(1152), dim3(256), 0, stream, x, xt);
    hipLaunchKernelGGL(dcn_prep_weight, dim3(144), dim3(256), 0, stream, w, wA);
    hipLaunchKernelGGL(dcn_fwd, dim3(768), dim3(384), 0, stream,
                       (const unsigned short*)xt, offset, mask, wA, out);
}

// Round 17
// 30.951 us; speedup vs baseline: 1.2301x; 1.2301x over previous
//
#include <hip/hip_runtime.h>

#define HWX 9216
#define CIN 64
#define COUT 64
#define SR 14
#define SC 24
#define SLOT 144          // bytes per staged pixel (128 data + 16 pad -> bank spread)

typedef __attribute__((ext_vector_type(8))) short short8;
typedef __attribute__((ext_vector_type(8))) _Float16 half8;
typedef __attribute__((ext_vector_type(2))) _Float16 half2v;
typedef __attribute__((ext_vector_type(4))) float f32x4;
typedef __attribute__((ext_vector_type(4))) unsigned int u32x4;

__device__ inline unsigned short f2h(float f) {
    union { _Float16 h; unsigned short u; } v;
    v.h = (_Float16)f;
    return v.u;
}
__device__ inline unsigned pack2h(float lo, float hi) {
    return (unsigned)f2h(lo) | ((unsigned)f2h(hi) << 16);
}

// merged pre-pass: blocks [0,1152) = NCHW f32 -> NHWC f16 transpose;
// blocks [1152,1296) = weight fragment prep. One launch instead of two.
__global__ __launch_bounds__(256) void dcn_pre(const float* __restrict__ x,
                                               unsigned* __restrict__ xt,
                                               const float* __restrict__ w,
                                               unsigned short* __restrict__ wA) {
    if (blockIdx.x < 1152) {
        __shared__ float tile[64][65];
        int n  = blockIdx.x / 144;
        int p0 = (blockIdx.x % 144) * 64;
        const float* xp = x + (size_t)n * CIN * HWX + p0;
        #pragma unroll
        for (int it = 0; it < 16; ++it) {
            int px = threadIdx.x & 63;
            int c  = (threadIdx.x >> 6) + it * 4;
            tile[c][px] = xp[c * HWX + px];
        }
        __syncthreads();
        unsigned* xo = xt + ((size_t)n * HWX + p0) * 32;
        #pragma unroll
        for (int it = 0; it < 8; ++it) {
            int c2 = threadIdx.x & 31;
            int px = (threadIdx.x >> 5) + it * 8;
            xo[px * 32 + c2] = pack2h(tile[2 * c2][px], tile[2 * c2 + 1][px]);
        }
    } else {
        // wA[idx], idx = ((step*4 + m0)*64 + lane)*8 + j  (f16 elements):
        // W[co = m0*16 + (lane&15)][kg = step*32 + (lane>>4)*8 + j], kg = kk*64 + c
        int idx = (blockIdx.x - 1152) * 256 + threadIdx.x;  // 36864 total
        int j    = idx & 7;
        int lane = (idx >> 3) & 63;
        int m0   = (idx >> 9) & 3;
        int step = idx >> 11;
        int co = m0 * 16 + (lane & 15);
        int kg = step * 32 + ((lane >> 4) << 3) + j;
        int kk = kg >> 6;
        int c  = kg & 63;
        wA[idx] = f2h(w[(co * 64 + c) * 9 + kk]);
    }
}

// 16x6 output tile, 6 waves/block, 768 blocks = exactly 3 blocks/CU resident
// (48,384B LDS), zero tail. f16 sampling pipeline (R13). Per-tap body (R14):
// ALL 8 ds_read_b128 issued back-to-back, ONE fallback branch, then both
// halves' blend+MFMA straight-line. [R16 lesson: explicit SW pipelining
// around the divergent fallback regresses — compiler serializes it.]
__global__ __launch_bounds__(384, 4) void dcn_fwd(const unsigned short* __restrict__ xt,
                                                  const float* __restrict__ offset,
                                                  const float* __restrict__ mask,
                                                  const unsigned short* __restrict__ wA,
                                                  float* __restrict__ out) {
    __shared__ __align__(16) char ldsx[SR * SC * SLOT];   // 48,384 B

    int bid = blockIdx.x;
    int swz = (bid & 7) * 96 + (bid >> 3);   // bijective XCD swizzle (768 = 8*96)
    int n   = swz / 96;                      // image <-> XCD
    int t0  = swz % 96;
    int r0  = (t0 / 6) * 6;                  // tile origin: 16 wide x 6 tall
    int c0  = (t0 % 6) * 16;

    int sy0 = r0 - 4;          // fixed window, clamped staging
    int sx0 = c0 - 4;

    const unsigned short* xn = xt + (size_t)n * HWX * 64;

    int wave = threadIdx.x >> 6;
    int lane = threadIdx.x & 63;
    int l15  = lane & 15;
    int lg   = lane >> 4;

    int ho = r0 + wave;
    int wo = c0 + l15;

    // hoisted offset/mask loads: all 27 in flight at once
    float dyv[9], dxv[9], mv[9];
    #pragma unroll
    for (int kk = 0; kk < 9; ++kk) {
        dyv[kk] = offset[((n * 18 + 2 * kk + 0) * 96 + ho) * 96 + wo];
        dxv[kk] = offset[((n * 18 + 2 * kk + 1) * 96 + ho) * 96 + wo];
        mv[kk]  = mask[((n * 9 + kk) * 96 + ho) * 96 + wo];
    }

    // stage 14x24 window: 2688 16B chunks = 7 iters * 384 threads
    #pragma unroll
    for (int it = 0; it < 7; ++it) {
        int i  = threadIdx.x + it * 384;
        int s  = i >> 3, ch = i & 7;
        int ly = s / SC, lx = s - ly * SC;
        int gy = min(max(sy0 + ly, 0), 95);
        int gx = min(max(sx0 + lx, 0), 95);
        *(u32x4*)(ldsx + s * SLOT + ch * 16) =
            *((const u32x4*)(xn + (gy * 96 + gx) * 64) + ch);
    }
    __syncthreads();

    f32x4 acc[4] = {f32x4{0,0,0,0}, f32x4{0,0,0,0}, f32x4{0,0,0,0}, f32x4{0,0,0,0}};

    int oh0 = lg * 16;        // half0 byte offset within pixel slot
    int oh1 = 64 + lg * 16;   // half1
    int ch0 = lg * 8;         // half0 element offset for global fallback
    int ch1 = 32 + lg * 8;    // half1

    #pragma unroll
    for (int kk = 0; kk < 9; ++kk) {
        int ky = kk / 3, kx = kk % 3;
        float dy = dyv[kk];
        float dx = dxv[kk];
        float m  = mv[kk];

        float py = dy + (float)(ky + ho - 1);
        float px = dx + (float)(kx + wo - 1);
        float y0f = floorf(py), x0f = floorf(px);
        float wy1 = py - y0f,  wx1 = px - x0f;
        float wy0 = 1.f - wy1, wx0 = 1.f - wx1;
        int y0 = (int)y0f, x0 = (int)x0f;
        int y1 = y0 + 1,   x1 = x0 + 1;
        bool vy0 = (y0 >= 0) && (y0 < 96);
        bool vy1 = (y1 >= 0) && (y1 < 96);
        bool vx0 = (x0 >= 0) && (x0 < 96);
        bool vx1 = (x1 >= 0) && (x1 < 96);
        int y0c = min(max(y0, 0), 95), y1c = min(max(y1, 0), 95);
        int x0c = min(max(x0, 0), 95), x1c = min(max(x1, 0), 95);
        float w00 = wy0 * wx0 * m * ((vy0 && vx0) ? 1.f : 0.f);
        float w01 = wy0 * wx1 * m * ((vy0 && vx1) ? 1.f : 0.f);
        float w10 = wy1 * wx0 * m * ((vy1 && vx0) ? 1.f : 0.f);
        float w11 = wy1 * wx1 * m * ((vy1 && vx1) ? 1.f : 0.f);

        _Float16 h00 = (_Float16)w00, h01 = (_Float16)w01;
        _Float16 h10 = (_Float16)w10, h11 = (_Float16)w11;
        half2v W00 = {h00, h00}, W01 = {h01, h01}, W10 = {h10, h10}, W11 = {h11, h11};

        bool local = (y0c >= sy0) & (y1c <= sy0 + SR - 1) &
                     (x0c >= sx0) & (x1c <= sx0 + SC - 1);
        int ly0 = min(max(y0c - sy0, 0), SR - 1);
        int ly1 = min(max(y1c - sy0, 0), SR - 1);
        int lx0 = min(max(x0c - sx0, 0), SC - 1);
        int lx1 = min(max(x1c - sx0, 0), SC - 1);
        int s00 = (ly0 * SC + lx0) * SLOT;
        int s01 = (ly0 * SC + lx1) * SLOT;
        int s10 = (ly1 * SC + lx0) * SLOT;
        int s11 = (ly1 * SC + lx1) * SLOT;

        // ---- ALL 8 LDS reads up front (8-deep outstanding lgkm) ----
        union { u32x4 u; half2v h[4]; } a00, a01, a10, a11, b00, b01, b10, b11, rA, rB;
        a00.u = *(const u32x4*)(ldsx + s00 + oh0);
        a01.u = *(const u32x4*)(ldsx + s01 + oh0);
        a10.u = *(const u32x4*)(ldsx + s10 + oh0);
        a11.u = *(const u32x4*)(ldsx + s11 + oh0);
        b00.u = *(const u32x4*)(ldsx + s00 + oh1);
        b01.u = *(const u32x4*)(ldsx + s01 + oh1);
        b10.u = *(const u32x4*)(ldsx + s10 + oh1);
        b11.u = *(const u32x4*)(ldsx + s11 + oh1);

        // ---- single per-tap fallback branch (rare lanes) ----
        if (__builtin_expect(!local, 0)) {
            int g00 = (y0c * 96 + x0c) * 64;
            int g01 = (y0c * 96 + x1c) * 64;
            int g10 = (y1c * 96 + x0c) * 64;
            int g11 = (y1c * 96 + x1c) * 64;
            a00.u = *(const u32x4*)(xn + g00 + ch0);
            a01.u = *(const u32x4*)(xn + g01 + ch0);
            a10.u = *(const u32x4*)(xn + g10 + ch0);
            a11.u = *(const u32x4*)(xn + g11 + ch0);
            b00.u = *(const u32x4*)(xn + g00 + ch1);
            b01.u = *(const u32x4*)(xn + g01 + ch1);
            b10.u = *(const u32x4*)(xn + g10 + ch1);
            b11.u = *(const u32x4*)(xn + g11 + ch1);
        }

        // ---- both halves blend + MFMA, straight-line ----
        #pragma unroll
        for (int p = 0; p < 4; ++p) {
            rA.h[p] = a00.h[p] * W00 + a01.h[p] * W01 + a10.h[p] * W10 + a11.h[p] * W11;
            rB.h[p] = b00.h[p] * W00 + b01.h[p] * W01 + b10.h[p] * W10 + b11.h[p] * W11;
        }
        half8 bfragA = *(half8*)&rA;
        half8 bfragB = *(half8*)&rB;

        {
            int step = kk * 2;
            const half8* wp = (const half8*)(wA + (step * 256 + lane) * 8);
            acc[0] = __builtin_amdgcn_mfma_f32_16x16x32_f16(wp[0],   bfragA, acc[0], 0, 0, 0);
            acc[1] = __builtin_amdgcn_mfma_f32_16x16x32_f16(wp[64],  bfragA, acc[1], 0, 0, 0);
            acc[2] = __builtin_amdgcn_mfma_f32_16x16x32_f16(wp[128], bfragA, acc[2], 0, 0, 0);
            acc[3] = __builtin_amdgcn_mfma_f32_16x16x32_f16(wp[192], bfragA, acc[3], 0, 0, 0);
        }
        {
            int step = kk * 2 + 1;
            const half8* wp = (const half8*)(wA + (step * 256 + lane) * 8);
            acc[0] = __builtin_amdgcn_mfma_f32_16x16x32_f16(wp[0],   bfragB, acc[0], 0, 0, 0);
            acc[1] = __builtin_amdgcn_mfma_f32_16x16x32_f16(wp[64],  bfragB, acc[1], 0, 0, 0);
            acc[2] = __builtin_amdgcn_mfma_f32_16x16x32_f16(wp[128], bfragB, acc[2], 0, 0, 0);
            acc[3] = __builtin_amdgcn_mfma_f32_16x16x32_f16(wp[192], bfragB, acc[3], 0, 0, 0);
        }
    }

    // D: lane l, reg r -> co = m0*16 + lg*4 + r, pixel col = l15
    size_t obase = (size_t)n * COUT * HWX + (size_t)ho * 96 + wo;
    #pragma unroll
    for (int m0 = 0; m0 < 4; ++m0) {
        #pragma unroll
        for (int r = 0; r < 4; ++r) {
            int co = m0 * 16 + lg * 4 + r;
            out[obase + (size_t)co * HWX] = acc[m0][r];
        }
    }
}

extern "C" void kernel_launch(void* const* d_in, const int* in_sizes, int n_in,
                              void* d_out, int out_size, void* d_ws, size_t ws_size,
                              hipStream_t stream) {
    const float* x      = (const float*)d_in[0];
    const float* offset = (const float*)d_in[1];
    const float* mask   = (const float*)d_in[2];
    const float* w      = (const float*)d_in[3];
    float* out = (float*)d_out;
    unsigned* xt       = (unsigned*)d_ws;                                    // 9,437,184 B
    unsigned short* wA = (unsigned short*)((char*)d_ws + (size_t)8 * HWX * 64 * 2); // +73,728 B

    hipLaunchKernelGGL(dcn_pre, dim3(1296), dim3(256), 0, stream, x, xt, w, wA);
    hipLaunchKernelGGL(dcn_fwd, dim3(768), dim3(384), 0, stream,
                       (const unsigned short*)xt, offset, mask, wA, out);
}